// Round 1
// baseline (6025.307 us; speedup 1.0000x reference)
//
#include <hip/hip_runtime.h>
#include <cstdint>

// AttCM: fused conv-stack + spatial attention, fp32 baseline.
// Shapes: B=8, C=256, H=W=64, HW=4096.
//
// Pipeline:
//   y1 = relu(W1 x)            64ch
//   y2 = relu(W2 y1)          128ch
//   xf = relu(W3 y2)          256ch
//   q/k/v = Wq/Wk/Wv xf       256ch (with bias, no relu)
//   t1 = relu(conv3x3(xf,wb1)); cb = conv3x3(t1,wb2)   (cb lives in d_out)
//   S[r,t] = sum_c k[c,r] q[c,t];  A = row-softmax(S) (softmax over t)
//   out[c,t] = alpha*cb[c,t] + beta * sum_r v[c,r] * exp(S[r,t]-M_r)/Z_r
// Two-pass attention: pass1 computes per-row (M_r, Z_r); pass2 recomputes S
// tile-wise and contracts with V (avoids materializing the 537MB A matrix).

#define HW 4096
#define NB 8

// ---------------- 1x1 conv as GEMM ----------------
// Y[b][m][p] = act( sum_k W[m][k] * X[b][k][p] + bias[m] )
// 64x64 tile, 4x4 microtile, K staged in chunks of 16.
__global__ __launch_bounds__(256) void gemm1x1(
    const float* __restrict__ W, const float* __restrict__ bias,
    const float* __restrict__ X, float* __restrict__ Y,
    int M, int K, int doRelu) {
  __shared__ float As[16][64];  // As[kk][m]
  __shared__ float Bs[16][64];  // Bs[kk][n]
  const int b  = blockIdx.z;
  const int m0 = blockIdx.y * 64;
  const int n0 = blockIdx.x * 64;
  const int tid = threadIdx.x;
  const int tx = tid & 15, ty = tid >> 4;
  const int lo = tid & 63, hi = tid >> 6;
  const float* Xb = X + (size_t)b * K * HW;
  float acc[4][4] = {};
  for (int k0 = 0; k0 < K; k0 += 16) {
#pragma unroll
    for (int it = 0; it < 4; it++) {
      const int kk = hi + it * 4;
      // W read: strided (stride K) but small + L2-resident; LDS write conflict-free
      As[kk][lo] = W[(size_t)(m0 + lo) * K + k0 + kk];
      // X read: coalesced along positions
      Bs[kk][lo] = Xb[(size_t)(k0 + kk) * HW + n0 + lo];
    }
    __syncthreads();
#pragma unroll
    for (int kk = 0; kk < 16; kk++) {
      float a[4], bv[4];
#pragma unroll
      for (int i = 0; i < 4; i++) a[i] = As[kk][ty * 4 + i];
#pragma unroll
      for (int j = 0; j < 4; j++) bv[j] = Bs[kk][tx * 4 + j];
#pragma unroll
      for (int i = 0; i < 4; i++)
#pragma unroll
        for (int j = 0; j < 4; j++)
          acc[i][j] = fmaf(a[i], bv[j], acc[i][j]);
    }
    __syncthreads();
  }
  float* Yb = Y + (size_t)b * M * HW;
#pragma unroll
  for (int i = 0; i < 4; i++) {
    const int m = m0 + ty * 4 + i;
    const float bb = bias[m];
#pragma unroll
    for (int j = 0; j < 4; j++) {
      float v = acc[i][j] + bb;
      if (doRelu) v = fmaxf(v, 0.0f);
      Yb[(size_t)m * HW + n0 + tx * 4 + j] = v;
    }
  }
}

// ---------------- 3x3 conv (pad=1), 256->256 ----------------
// Block: one image row y, 64 output channels, 64 pixels. Implicit GEMM over
// (c,dy,dx): input rows staged with halo, weights staged per 8-channel chunk.
__global__ __launch_bounds__(256) void conv3x3(
    const float* __restrict__ in, const float* __restrict__ w,
    const float* __restrict__ bias, float* __restrict__ out, int doRelu) {
  __shared__ float Ins[8][3][68];   // [c][dy][col], col = x+1 in [0,65]
  __shared__ float Ws[8][9][64];    // [c][dy*3+dx][o]
  const int y  = blockIdx.x;
  const int o0 = blockIdx.y * 64;
  const int b  = blockIdx.z;
  const int tid = threadIdx.x;
  const int tx = tid & 15, ty = tid >> 4;
  float acc[4][4] = {};
  for (int c0 = 0; c0 < 256; c0 += 8) {
    // stage input rows (coalesced along x, zero-padded halo)
    for (int i = tid; i < 8 * 3 * 66; i += 256) {
      int c = i / 198;
      int rem = i - c * 198;
      int dy = rem / 66;
      int col = rem - dy * 66;
      int xx = col - 1;
      int yy = y + dy - 1;
      float v = 0.0f;
      if (xx >= 0 && xx < 64 && yy >= 0 && yy < 64)
        v = in[((size_t)(b * 256 + c0 + c)) * HW + yy * 64 + xx];
      Ins[c][dy][col] = v;
    }
    // stage weights: lanes along o (strided global, L2-resident; LDS conflict-free)
    {
      const int o = tid & 63;
      for (int r = tid >> 6; r < 72; r += 4)
        Ws[r / 9][r - (r / 9) * 9][o] = w[(size_t)(o0 + o) * 2304 + c0 * 9 + r];
    }
    __syncthreads();
#pragma unroll
    for (int c = 0; c < 8; c++) {
#pragma unroll
      for (int dy = 0; dy < 3; dy++) {
        float bb[6];
#pragma unroll
        for (int j = 0; j < 6; j++) bb[j] = Ins[c][dy][tx * 4 + j];
#pragma unroll
        for (int dx = 0; dx < 3; dx++) {
          float a[4];
#pragma unroll
          for (int i = 0; i < 4; i++) a[i] = Ws[c][dy * 3 + dx][ty * 4 + i];
#pragma unroll
          for (int i = 0; i < 4; i++)
#pragma unroll
            for (int j = 0; j < 4; j++)
              acc[i][j] = fmaf(a[i], bb[j + dx], acc[i][j]);
        }
      }
    }
    __syncthreads();
  }
#pragma unroll
  for (int i = 0; i < 4; i++) {
    const int o = o0 + ty * 4 + i;
    const float b0 = bias[o];
#pragma unroll
    for (int j = 0; j < 4; j++) {
      float v = acc[i][j] + b0;
      if (doRelu) v = fmaxf(v, 0.0f);
      out[((size_t)(b * 256 + o)) * HW + y * 64 + tx * 4 + j] = v;
    }
  }
}

// ---------------- attention pass 1: per-row max & sum(exp) ----------------
// Block: 64 rows r (k-positions) x batch b; sweeps all 4096 t (q-positions).
__global__ __launch_bounds__(256) void attn_rowstats(
    const float* __restrict__ kb, const float* __restrict__ qb,
    float* __restrict__ Mrow, float* __restrict__ Zrow) {
  __shared__ float As[16][64];  // k chunk [kk][r]
  __shared__ float Bs[16][64];  // q chunk [kk][t]
  const int b  = blockIdx.y;
  const int r0 = blockIdx.x * 64;
  const int tid = threadIdx.x;
  const int tx = tid & 15, ty = tid >> 4;
  const int lo = tid & 63, hi = tid >> 6;
  const float* kbb = kb + (size_t)b * 256 * HW;
  const float* qbb = qb + (size_t)b * 256 * HW;
  float m[4], z[4];
#pragma unroll
  for (int i = 0; i < 4; i++) { m[i] = -1e30f; z[i] = 0.0f; }
  for (int t0 = 0; t0 < HW; t0 += 64) {
    float s[4][4] = {};
    for (int c0 = 0; c0 < 256; c0 += 16) {
#pragma unroll
      for (int it = 0; it < 4; it++) {
        const int kk = hi + it * 4;
        As[kk][lo] = kbb[(size_t)(c0 + kk) * HW + r0 + lo];
        Bs[kk][lo] = qbb[(size_t)(c0 + kk) * HW + t0 + lo];
      }
      __syncthreads();
#pragma unroll
      for (int kk = 0; kk < 16; kk++) {
        float a[4], bv[4];
#pragma unroll
        for (int i = 0; i < 4; i++) a[i] = As[kk][ty * 4 + i];
#pragma unroll
        for (int j = 0; j < 4; j++) bv[j] = Bs[kk][tx * 4 + j];
#pragma unroll
        for (int i = 0; i < 4; i++)
#pragma unroll
          for (int j = 0; j < 4; j++)
            s[i][j] = fmaf(a[i], bv[j], s[i][j]);
      }
      __syncthreads();
    }
    // online max/sum update, ~1 exp per element
#pragma unroll
    for (int i = 0; i < 4; i++)
#pragma unroll
      for (int j = 0; j < 4; j++) {
        const float sv = s[i][j];
        if (sv > m[i]) { z[i] *= __expf(m[i] - sv); m[i] = sv; }
        z[i] += __expf(sv - m[i]);
      }
  }
  // merge across the 16 lanes (tx) that share each row group
#pragma unroll
  for (int i = 0; i < 4; i++) {
    for (int off = 1; off < 16; off <<= 1) {
      const float mo = __shfl_xor(m[i], off, 16);
      const float zo = __shfl_xor(z[i], off, 16);
      const float mn = fmaxf(m[i], mo);
      z[i] = z[i] * __expf(m[i] - mn) + zo * __expf(mo - mn);
      m[i] = mn;
    }
  }
  if (tx == 0) {
#pragma unroll
    for (int i = 0; i < 4; i++) {
      const int r = r0 + ty * 4 + i;
      Mrow[(size_t)b * HW + r] = m[i];
      Zrow[(size_t)b * HW + r] = z[i];
    }
  }
}

// ---------------- attention pass 2 + final combine ----------------
// Block: batch b, 64 output positions t; all 256 channels (4 c-chunks of 64).
// Loop over r-chunks of 64: recompute S tile -> P = exp(S-M_r)/Z_r -> O += V*P.
__global__ __launch_bounds__(256) void attn_pass2(
    const float* __restrict__ kb, const float* __restrict__ qb,
    const float* __restrict__ vb, const float* __restrict__ Mrow,
    const float* __restrict__ Zrow, const float* __restrict__ cb,
    const float* __restrict__ alphap, const float* __restrict__ betap,
    float* __restrict__ out) {
  __shared__ float As[16][64];   // k chunk [kk][r]
  __shared__ float Bs[16][64];   // q chunk [kk][t]
  __shared__ float Ps[64][67];   // P tile [r][t] (pad 67: 3r+t banks)
  __shared__ float Vs[64][67];   // V tile [r][c]
  const int b  = blockIdx.y;
  const int t0 = blockIdx.x * 64;
  const int tid = threadIdx.x;
  const int tx = tid & 15, ty = tid >> 4;
  const int lo = tid & 63, hi = tid >> 6;
  const float* kbb = kb + (size_t)b * 256 * HW;
  const float* qbb = qb + (size_t)b * 256 * HW;
  const float* vbb = vb + (size_t)b * 256 * HW;
  float acc[4][4][4] = {};  // [c-chunk][i(c)][j(t)]
  for (int r0 = 0; r0 < HW; r0 += 64) {
    // --- S tile: 64r x 64t over K=256 channels
    float s[4][4] = {};
    for (int c0 = 0; c0 < 256; c0 += 16) {
#pragma unroll
      for (int it = 0; it < 4; it++) {
        const int kk = hi + it * 4;
        As[kk][lo] = kbb[(size_t)(c0 + kk) * HW + r0 + lo];
        Bs[kk][lo] = qbb[(size_t)(c0 + kk) * HW + t0 + lo];
      }
      __syncthreads();
#pragma unroll
      for (int kk = 0; kk < 16; kk++) {
        float a[4], bv[4];
#pragma unroll
        for (int i = 0; i < 4; i++) a[i] = As[kk][ty * 4 + i];
#pragma unroll
        for (int j = 0; j < 4; j++) bv[j] = Bs[kk][tx * 4 + j];
#pragma unroll
        for (int i = 0; i < 4; i++)
#pragma unroll
          for (int j = 0; j < 4; j++)
            s[i][j] = fmaf(a[i], bv[j], s[i][j]);
      }
      __syncthreads();
    }
    // --- P tile: exp(S - M_r)/Z_r  (thread owns rows r0+ty*4+i, cols t0+tx*4+j)
#pragma unroll
    for (int i = 0; i < 4; i++) {
      const int r = r0 + ty * 4 + i;
      const float Mr = Mrow[(size_t)b * HW + r];
      const float rZ = 1.0f / Zrow[(size_t)b * HW + r];
#pragma unroll
      for (int j = 0; j < 4; j++)
        Ps[ty * 4 + i][tx * 4 + j] = __expf(s[i][j] - Mr) * rZ;
    }
    // --- O += V(c,r) * P(r,t), 4 chunks of 64 channels
#pragma unroll
    for (int cc4 = 0; cc4 < 4; cc4++) {
      {
        const int rr = tid & 63, cc0 = tid >> 6;
#pragma unroll
        for (int it = 0; it < 16; it++)
          Vs[rr][cc0 + it * 4] =
              vbb[(size_t)(cc4 * 64 + cc0 + it * 4) * HW + r0 + rr];
      }
      __syncthreads();
#pragma unroll 8
      for (int rr = 0; rr < 64; rr++) {
        float a[4], p[4];
#pragma unroll
        for (int i = 0; i < 4; i++) a[i] = Vs[rr][ty * 4 + i];
#pragma unroll
        for (int j = 0; j < 4; j++) p[j] = Ps[rr][tx * 4 + j];
#pragma unroll
        for (int i = 0; i < 4; i++)
#pragma unroll
          for (int j = 0; j < 4; j++)
            acc[cc4][i][j] = fmaf(a[i], p[j], acc[cc4][i][j]);
      }
      __syncthreads();
    }
  }
  const float alpha = alphap[0];
  const float beta  = betap[0];
#pragma unroll
  for (int cc4 = 0; cc4 < 4; cc4++)
#pragma unroll
    for (int i = 0; i < 4; i++)
#pragma unroll
      for (int j = 0; j < 4; j++) {
        const int c = cc4 * 64 + ty * 4 + i;
        const size_t idx = ((size_t)(b * 256 + c)) * HW + t0 + tx * 4 + j;
        out[idx] = alpha * cb[idx] + beta * acc[cc4][i][j];
      }
}

extern "C" void kernel_launch(void* const* d_in, const int* in_sizes, int n_in,
                              void* d_out, int out_size, void* d_ws, size_t ws_size,
                              hipStream_t stream) {
  (void)in_sizes; (void)n_in; (void)out_size; (void)ws_size;
  const float* x   = (const float*)d_in[0];
  const float* w1  = (const float*)d_in[1];
  const float* b1  = (const float*)d_in[2];
  const float* w2  = (const float*)d_in[3];
  const float* b2  = (const float*)d_in[4];
  const float* w3  = (const float*)d_in[5];
  const float* b3  = (const float*)d_in[6];
  const float* wb1 = (const float*)d_in[7];
  const float* bb1 = (const float*)d_in[8];
  const float* wb2 = (const float*)d_in[9];
  const float* bb2 = (const float*)d_in[10];
  const float* wq  = (const float*)d_in[11];
  const float* bq  = (const float*)d_in[12];
  const float* wk  = (const float*)d_in[13];
  const float* bk  = (const float*)d_in[14];
  const float* wv  = (const float*)d_in[15];
  const float* bv  = (const float*)d_in[16];
  const float* alpha = (const float*)d_in[17];
  const float* beta  = (const float*)d_in[18];
  float* out = (float*)d_out;
  float* ws  = (float*)d_ws;

  // workspace slots (floats), 5 x 8.4M + stats = ~168MB; cb aliased onto d_out
  const size_t SZ = (size_t)NB * 256 * HW;  // 8,388,608
  float* t1 = ws;            // also y1 (2M floats, dead before conv1 writes t1)
  float* qb = ws + SZ;       // also y2 (4M floats, dead before q is written)
  float* xf = ws + 2 * SZ;
  float* kb = ws + 3 * SZ;
  float* vb = ws + 4 * SZ;
  float* Mrow = ws + 5 * SZ;
  float* Zrow = Mrow + (size_t)NB * HW;
  float* y1 = t1;
  float* y2 = qb;
  float* cb = out;           // conv branch output lives in d_out, combined in-place

  gemm1x1<<<dim3(64, 1, NB), 256, 0, stream>>>(w1, b1, x,  y1,  64, 256, 1);
  gemm1x1<<<dim3(64, 2, NB), 256, 0, stream>>>(w2, b2, y1, y2, 128,  64, 1);
  gemm1x1<<<dim3(64, 4, NB), 256, 0, stream>>>(w3, b3, y2, xf, 256, 128, 1);
  gemm1x1<<<dim3(64, 4, NB), 256, 0, stream>>>(wq, bq, xf, qb, 256, 256, 0);
  gemm1x1<<<dim3(64, 4, NB), 256, 0, stream>>>(wk, bk, xf, kb, 256, 256, 0);
  gemm1x1<<<dim3(64, 4, NB), 256, 0, stream>>>(wv, bv, xf, vb, 256, 256, 0);
  conv3x3<<<dim3(64, 4, NB), 256, 0, stream>>>(xf, wb1, bb1, t1, 1);
  conv3x3<<<dim3(64, 4, NB), 256, 0, stream>>>(t1, wb2, bb2, cb, 0);
  attn_rowstats<<<dim3(64, NB), 256, 0, stream>>>(kb, qb, Mrow, Zrow);
  attn_pass2<<<dim3(64, NB), 256, 0, stream>>>(kb, qb, vb, Mrow, Zrow, cb,
                                               alpha, beta, out);
}

// Round 2
// 2085.684 us; speedup vs baseline: 2.8889x; 2.8889x over previous
//
#include <hip/hip_runtime.h>
#include <cstdint>

// AttCM R1: attention (rowstats + pass2) moved to bf16 MFMA (16x16x32).
// Convs stay fp32 (proven R0 code). q,k stored transposed bf16 [b][t][c];
// v stored bf16 natural [b][c][t]. XOR-swizzled LDS (chunk ^= row&7, 16B
// units) for conflict-free ds_read_b128 fragments.
// Shapes: B=8, C=256, HW=4096.

#define HW 4096
#define NB 8

typedef __attribute__((ext_vector_type(8))) short short8;   // 8 bf16 = 4 VGPR
typedef __attribute__((ext_vector_type(4))) float f32x4;    // MFMA C/D

static __device__ __forceinline__ unsigned short f2bf(float x) {
  unsigned u = __float_as_uint(x);
  u += 0x7FFFu + ((u >> 16) & 1u);           // round-to-nearest-even
  return (unsigned short)(u >> 16);
}

// ---------------- 1x1 conv as GEMM (fp32, unchanged from R0) ----------------
__global__ __launch_bounds__(256) void gemm1x1(
    const float* __restrict__ W, const float* __restrict__ bias,
    const float* __restrict__ X, float* __restrict__ Y,
    int M, int K, int doRelu) {
  __shared__ float As[16][64];
  __shared__ float Bs[16][64];
  const int b  = blockIdx.z;
  const int m0 = blockIdx.y * 64;
  const int n0 = blockIdx.x * 64;
  const int tid = threadIdx.x;
  const int tx = tid & 15, ty = tid >> 4;
  const int lo = tid & 63, hi = tid >> 6;
  const float* Xb = X + (size_t)b * K * HW;
  float acc[4][4] = {};
  for (int k0 = 0; k0 < K; k0 += 16) {
#pragma unroll
    for (int it = 0; it < 4; it++) {
      const int kk = hi + it * 4;
      As[kk][lo] = W[(size_t)(m0 + lo) * K + k0 + kk];
      Bs[kk][lo] = Xb[(size_t)(k0 + kk) * HW + n0 + lo];
    }
    __syncthreads();
#pragma unroll
    for (int kk = 0; kk < 16; kk++) {
      float a[4], bv[4];
#pragma unroll
      for (int i = 0; i < 4; i++) a[i] = As[kk][ty * 4 + i];
#pragma unroll
      for (int j = 0; j < 4; j++) bv[j] = Bs[kk][tx * 4 + j];
#pragma unroll
      for (int i = 0; i < 4; i++)
#pragma unroll
        for (int j = 0; j < 4; j++)
          acc[i][j] = fmaf(a[i], bv[j], acc[i][j]);
    }
    __syncthreads();
  }
  float* Yb = Y + (size_t)b * M * HW;
#pragma unroll
  for (int i = 0; i < 4; i++) {
    const int m = m0 + ty * 4 + i;
    const float bb = bias[m];
#pragma unroll
    for (int j = 0; j < 4; j++) {
      float v = acc[i][j] + bb;
      if (doRelu) v = fmaxf(v, 0.0f);
      Yb[(size_t)m * HW + n0 + tx * 4 + j] = v;
    }
  }
}

// ---------------- 3x3 conv (fp32, unchanged from R0) ----------------
__global__ __launch_bounds__(256) void conv3x3(
    const float* __restrict__ in, const float* __restrict__ w,
    const float* __restrict__ bias, float* __restrict__ out, int doRelu) {
  __shared__ float Ins[8][3][68];
  __shared__ float Ws[8][9][64];
  const int y  = blockIdx.x;
  const int o0 = blockIdx.y * 64;
  const int b  = blockIdx.z;
  const int tid = threadIdx.x;
  const int tx = tid & 15, ty = tid >> 4;
  float acc[4][4] = {};
  for (int c0 = 0; c0 < 256; c0 += 8) {
    for (int i = tid; i < 8 * 3 * 66; i += 256) {
      int c = i / 198;
      int rem = i - c * 198;
      int dy = rem / 66;
      int col = rem - dy * 66;
      int xx = col - 1;
      int yy = y + dy - 1;
      float v = 0.0f;
      if (xx >= 0 && xx < 64 && yy >= 0 && yy < 64)
        v = in[((size_t)(b * 256 + c0 + c)) * HW + yy * 64 + xx];
      Ins[c][dy][col] = v;
    }
    {
      const int o = tid & 63;
      for (int r = tid >> 6; r < 72; r += 4)
        Ws[r / 9][r - (r / 9) * 9][o] = w[(size_t)(o0 + o) * 2304 + c0 * 9 + r];
    }
    __syncthreads();
#pragma unroll
    for (int c = 0; c < 8; c++) {
#pragma unroll
      for (int dy = 0; dy < 3; dy++) {
        float bb[6];
#pragma unroll
        for (int j = 0; j < 6; j++) bb[j] = Ins[c][dy][tx * 4 + j];
#pragma unroll
        for (int dx = 0; dx < 3; dx++) {
          float a[4];
#pragma unroll
          for (int i = 0; i < 4; i++) a[i] = Ws[c][dy * 3 + dx][ty * 4 + i];
#pragma unroll
          for (int i = 0; i < 4; i++)
#pragma unroll
            for (int j = 0; j < 4; j++)
              acc[i][j] = fmaf(a[i], bb[j + dx], acc[i][j]);
        }
      }
    }
    __syncthreads();
  }
#pragma unroll
  for (int i = 0; i < 4; i++) {
    const int o = o0 + ty * 4 + i;
    const float b0 = bias[o];
#pragma unroll
    for (int j = 0; j < 4; j++) {
      float v = acc[i][j] + b0;
      if (doRelu) v = fmaxf(v, 0.0f);
      out[((size_t)(b * 256 + o)) * HW + y * 64 + tx * 4 + j] = v;
    }
  }
}

// ---------------- fp32 [b][c][t] -> bf16 transposed [b][t][c] ----------------
__global__ __launch_bounds__(256) void transpose_cvt(
    const float* __restrict__ in, unsigned short* __restrict__ outT) {
  __shared__ float Ts[64][65];
  const int t0 = blockIdx.x * 64;
  const int c0 = blockIdx.y * 64;
  const int b  = blockIdx.z;
  const int tid = threadIdx.x;
#pragma unroll
  for (int it = 0; it < 4; it++) {
    int id = tid + it * 256;
    int c = id >> 4, f4 = id & 15;
    float4 v = *(const float4*)(in + ((size_t)(b * 256 + c0 + c)) * HW + t0 + f4 * 4);
    Ts[c][f4 * 4 + 0] = v.x; Ts[c][f4 * 4 + 1] = v.y;
    Ts[c][f4 * 4 + 2] = v.z; Ts[c][f4 * 4 + 3] = v.w;
  }
  __syncthreads();
#pragma unroll
  for (int it = 0; it < 2; it++) {
    int id = tid + it * 256;
    int t = id >> 3, ch = id & 7;
    unsigned short h[8];
#pragma unroll
    for (int e = 0; e < 8; e++) h[e] = f2bf(Ts[ch * 8 + e][t]);
    int4 pk;
    pk.x = (int)((unsigned)h[0] | ((unsigned)h[1] << 16));
    pk.y = (int)((unsigned)h[2] | ((unsigned)h[3] << 16));
    pk.z = (int)((unsigned)h[4] | ((unsigned)h[5] << 16));
    pk.w = (int)((unsigned)h[6] | ((unsigned)h[7] << 16));
    ((int4*)outT)[((size_t)b * HW + t0 + t) * 32 + (c0 >> 3) + ch] = pk;
  }
}

// ---------------- fp32 -> bf16 (same layout) ----------------
__global__ void cvt_bf16(const float* __restrict__ in,
                         unsigned short* __restrict__ o, long n8) {
  long i = (long)blockIdx.x * blockDim.x + threadIdx.x;
  const long stride = (long)gridDim.x * blockDim.x;
  const float4* i4 = (const float4*)in;
  for (; i < n8; i += stride) {
    float4 a = i4[2 * i], b = i4[2 * i + 1];
    int4 pk;
    pk.x = (int)((unsigned)f2bf(a.x) | ((unsigned)f2bf(a.y) << 16));
    pk.y = (int)((unsigned)f2bf(a.z) | ((unsigned)f2bf(a.w) << 16));
    pk.z = (int)((unsigned)f2bf(b.x) | ((unsigned)f2bf(b.y) << 16));
    pk.w = (int)((unsigned)f2bf(b.z) | ((unsigned)f2bf(b.w) << 16));
    ((int4*)o)[i] = pk;
  }
}

// ---------------- attention pass 1 (MFMA): per-row max & 1/sum(exp) --------
// Block: 64 rows r, batch b. S[r,t] = sum_c kT[r][c] qT[t][c]; sweep t.
// A-frags (K rows) preloaded from global into regs; Q tile staged per t-iter.
__global__ __launch_bounds__(256) void attn_rowstats(
    const unsigned short* __restrict__ kT, const unsigned short* __restrict__ qT,
    float* __restrict__ Mrow, float* __restrict__ Zrow) {
  __shared__ int4 qs4[64][32];   // [t][c-chunks of 8 bf16], swizzled
  const int b = blockIdx.y;
  const int r0 = blockIdx.x * 64;
  const int tid = threadIdx.x;
  const int w = tid >> 6, l = tid & 63;
  const int l4 = l >> 4, l15 = l & 15;
  const int4* qT4 = (const int4*)qT + (size_t)b * HW * 32;
  const short8* kT8 = (const short8*)kT + ((size_t)b * HW + r0) * 32;
  short8 afr[8];                 // wave w owns rows [w*16, w*16+16)
#pragma unroll
  for (int ks = 0; ks < 8; ks++)
    afr[ks] = kT8[(size_t)(w * 16 + l15) * 32 + ks * 4 + l4];
  float m[4], z[4];
#pragma unroll
  for (int i = 0; i < 4; i++) { m[i] = -1e30f; z[i] = 0.0f; }
  for (int t0 = 0; t0 < HW; t0 += 64) {
    __syncthreads();
#pragma unroll
    for (int it = 0; it < 8; it++) {
      int id = tid + it * 256;
      int row = id >> 5, ch = id & 31;
      qs4[row][ch ^ (row & 7)] = qT4[(size_t)(t0 + row) * 32 + ch];
    }
    __syncthreads();
    f32x4 acc[4] = {{0.f,0.f,0.f,0.f},{0.f,0.f,0.f,0.f},
                    {0.f,0.f,0.f,0.f},{0.f,0.f,0.f,0.f}};
#pragma unroll
    for (int ks = 0; ks < 8; ks++) {
#pragma unroll
      for (int nf = 0; nf < 4; nf++) {
        int t = nf * 16 + l15;
        short8 bq = ((const short8*)qs4)[t * 32 + ((ks * 4 + l4) ^ (t & 7))];
        acc[nf] = __builtin_amdgcn_mfma_f32_16x16x32_bf16(afr[ks], bq, acc[nf], 0, 0, 0);
      }
    }
#pragma unroll
    for (int nf = 0; nf < 4; nf++)
#pragma unroll
      for (int r = 0; r < 4; r++) {
        float sv = acc[nf][r];
        if (sv > m[r]) { z[r] *= __expf(m[r] - sv); m[r] = sv; }
        z[r] += __expf(sv - m[r]);
      }
  }
  // merge across the 16 lanes (l15) sharing the same rows
#pragma unroll
  for (int r = 0; r < 4; r++) {
    for (int off = 1; off < 16; off <<= 1) {
      float mo = __shfl_xor(m[r], off, 16);
      float zo = __shfl_xor(z[r], off, 16);
      float mn = fmaxf(m[r], mo);
      z[r] = z[r] * __expf(m[r] - mn) + zo * __expf(mo - mn);
      m[r] = mn;
    }
  }
  if (l15 == 0) {
#pragma unroll
    for (int r = 0; r < 4; r++) {
      int rr = r0 + w * 16 + l4 * 4 + r;      // D row = (l>>4)*4 + reg
      Mrow[(size_t)b * HW + rr] = m[r];
      Zrow[(size_t)b * HW + rr] = 1.0f / z[r];   // store reciprocal
    }
  }
}

// ---------------- attention pass 2 (MFMA) + combine ----------------
// Block: t-tile 64, batch b. r-chunks of 128: S[128r][64t] -> P(bf16) -> PV.
// ks and vs share one 16KB LDS buffer (disjoint lifetimes).
__global__ __launch_bounds__(256, 2) void attn_pass2(
    const unsigned short* __restrict__ kT, const unsigned short* __restrict__ qT,
    const unsigned short* __restrict__ vB, const float* __restrict__ Mrow,
    const float* __restrict__ Zrow, const float* __restrict__ alphap,
    const float* __restrict__ betap, float* __restrict__ out) {
  __shared__ int4 qs4[64][32];   // 32KB [t][c]
  __shared__ int4 kvs4[1024];    // 16KB: S: [128r][8ch] ; PV: [64c][16ch]
  __shared__ int4 ps4[64][16];   // 16KB [t][r] bf16 (256B rows)
  const int b = blockIdx.y;
  const int t0 = blockIdx.x * 64;
  const int tid = threadIdx.x;
  const int w = tid >> 6, l = tid & 63;
  const int l4 = l >> 4, l15 = l & 15;
  const int4* qT4 = (const int4*)qT + ((size_t)b * HW + t0) * 32;
  const int4* kT4 = (const int4*)kT + (size_t)b * HW * 32;
  const int4* vB4 = (const int4*)vB;
  const float* Mb = Mrow + (size_t)b * HW;
  const float* Zb = Zrow + (size_t)b * HW;
  // stage Q once (swizzled)
#pragma unroll
  for (int it = 0; it < 8; it++) {
    int id = tid + it * 256;
    int row = id >> 5, ch = id & 31;
    qs4[row][ch ^ (row & 7)] = qT4[(size_t)row * 32 + ch];
  }
  f32x4 acc_o[4][4];             // [c-chunk][nf]
#pragma unroll
  for (int i = 0; i < 4; i++)
#pragma unroll
    for (int j = 0; j < 4; j++) acc_o[i][j] = {0.f, 0.f, 0.f, 0.f};
  __syncthreads();

  for (int r0 = 0; r0 < HW; r0 += 128) {
    // ---- S phase: S[128r][64t], wave w owns rows [w*32, w*32+32)
    f32x4 acc_s[2][4];
#pragma unroll
    for (int i = 0; i < 2; i++)
#pragma unroll
      for (int j = 0; j < 4; j++) acc_s[i][j] = {0.f, 0.f, 0.f, 0.f};
    for (int cc = 0; cc < 4; cc++) {           // c-chunks of 64
      __syncthreads();
#pragma unroll
      for (int it = 0; it < 4; it++) {         // stage K chunk: 128r x 8ch
        int id = tid + it * 256;
        int row = id >> 3, ch = id & 7;
        kvs4[row * 8 + (ch ^ (row & 7))] = kT4[(size_t)(r0 + row) * 32 + cc * 8 + ch];
      }
      __syncthreads();
#pragma unroll
      for (int kk = 0; kk < 2; kk++) {
        short8 bq[4];
#pragma unroll
        for (int nf = 0; nf < 4; nf++) {
          int t = nf * 16 + l15;
          bq[nf] = ((const short8*)qs4)[t * 32 + (((cc * 2 + kk) * 4 + l4) ^ (t & 7))];
        }
#pragma unroll
        for (int mfl = 0; mfl < 2; mfl++) {
          int r = w * 32 + mfl * 16 + l15;
          short8 ak = ((const short8*)kvs4)[r * 8 + ((kk * 4 + l4) ^ (r & 7))];
#pragma unroll
          for (int nf = 0; nf < 4; nf++)
            acc_s[mfl][nf] = __builtin_amdgcn_mfma_f32_16x16x32_bf16(ak, bq[nf], acc_s[mfl][nf], 0, 0, 0);
        }
      }
    }
    // ---- P = exp(S - M_r) * rZ_r -> ps[t][r] packed bf16 (b64 per frag)
#pragma unroll
    for (int mfl = 0; mfl < 2; mfl++) {
      int rbase = r0 + w * 32 + mfl * 16 + l4 * 4;   // rows rbase..rbase+3 (regs)
      f32x4 Mv = *(const f32x4*)(Mb + rbase);
      f32x4 Zv = *(const f32x4*)(Zb + rbase);
      int slot = w * 8 + mfl * 4 + l4;               // 8B slot within 256B row
#pragma unroll
      for (int nf = 0; nf < 4; nf++) {
        int t = nf * 16 + l15;
        unsigned lo = (unsigned)f2bf(__expf(acc_s[mfl][nf][0] - Mv[0]) * Zv[0])
                    | ((unsigned)f2bf(__expf(acc_s[mfl][nf][1] - Mv[1]) * Zv[1]) << 16);
        unsigned hi = (unsigned)f2bf(__expf(acc_s[mfl][nf][2] - Mv[2]) * Zv[2])
                    | ((unsigned)f2bf(__expf(acc_s[mfl][nf][3] - Mv[3]) * Zv[3]) << 16);
        int ch = slot >> 1;
        int fslot = ((ch ^ (t & 7)) << 1) | (slot & 1);
        ((unsigned long long*)ps4)[(size_t)t * 32 + fslot] =
            ((unsigned long long)hi << 32) | (unsigned long long)lo;
      }
    }
    // ---- PV phase: O[256c][64t] += V[c][r] * P[r][t], c-chunks of 64
#pragma unroll
    for (int cc4 = 0; cc4 < 4; cc4++) {
      __syncthreads();                        // prev PV reads done; ps visible
#pragma unroll
      for (int it = 0; it < 4; it++) {        // stage V chunk: 64c x 16ch
        int id = tid + it * 256;
        int row = id >> 4, ch = id & 15;
        kvs4[row * 16 + (ch ^ (row & 7))] =
            vB4[((size_t)(b * 256) + cc4 * 64 + row) * 512 + (r0 >> 3) + ch];
      }
      __syncthreads();
#pragma unroll
      for (int ks = 0; ks < 4; ks++) {        // r-ksteps of 32
        int c = w * 16 + l15;
        short8 av = ((const short8*)kvs4)[c * 16 + ((ks * 4 + l4) ^ (c & 7))];
#pragma unroll
        for (int nf = 0; nf < 4; nf++) {
          int t = nf * 16 + l15;
          short8 bp = ((const short8*)ps4)[t * 16 + ((ks * 4 + l4) ^ (t & 7))];
          acc_o[cc4][nf] = __builtin_amdgcn_mfma_f32_16x16x32_bf16(av, bp, acc_o[cc4][nf], 0, 0, 0);
        }
      }
    }
  }
  // ---- epilogue: out = alpha*cb + beta*attn   (cb already in out)
  const float alpha = alphap[0], beta = betap[0];
#pragma unroll
  for (int cc4 = 0; cc4 < 4; cc4++) {
    int cbase = cc4 * 64 + w * 16 + l4 * 4;
#pragma unroll
    for (int nf = 0; nf < 4; nf++) {
      int t = t0 + nf * 16 + l15;
#pragma unroll
      for (int r = 0; r < 4; r++) {
        size_t idx = ((size_t)(b * 256 + cbase + r)) * HW + t;
        out[idx] = alpha * out[idx] + beta * acc_o[cc4][nf][r];
      }
    }
  }
}

extern "C" void kernel_launch(void* const* d_in, const int* in_sizes, int n_in,
                              void* d_out, int out_size, void* d_ws, size_t ws_size,
                              hipStream_t stream) {
  (void)in_sizes; (void)n_in; (void)out_size; (void)ws_size;
  const float* x   = (const float*)d_in[0];
  const float* w1  = (const float*)d_in[1];
  const float* b1  = (const float*)d_in[2];
  const float* w2  = (const float*)d_in[3];
  const float* b2  = (const float*)d_in[4];
  const float* w3  = (const float*)d_in[5];
  const float* b3  = (const float*)d_in[6];
  const float* wb1 = (const float*)d_in[7];
  const float* bb1 = (const float*)d_in[8];
  const float* wb2 = (const float*)d_in[9];
  const float* bb2 = (const float*)d_in[10];
  const float* wq  = (const float*)d_in[11];
  const float* bq  = (const float*)d_in[12];
  const float* wk  = (const float*)d_in[13];
  const float* bk  = (const float*)d_in[14];
  const float* wv  = (const float*)d_in[15];
  const float* bv  = (const float*)d_in[16];
  const float* alpha = (const float*)d_in[17];
  const float* beta  = (const float*)d_in[18];
  float* out = (float*)d_out;
  float* ws  = (float*)d_ws;

  // ws layout (floats): xf[SZ] | scr[SZ] | qT,kT,vT bf16 (1.5*SZ) | M,Z
  const size_t SZ = (size_t)NB * 256 * HW;   // 8,388,608
  float* xf  = ws;
  float* scr = ws + SZ;                      // y1/y2, then q/k/v fp32, then t1
  float* y1  = scr;                          // SZ/4 floats
  float* y2  = scr + SZ / 4;                 // SZ/2 floats
  unsigned short* qTh = (unsigned short*)(ws + 2 * SZ);
  unsigned short* kTh = qTh + SZ;
  unsigned short* vTh = kTh + SZ;
  float* Mrow = ws + 2 * SZ + (3 * SZ) / 2;
  float* Zrow = Mrow + (size_t)NB * HW;

  gemm1x1<<<dim3(64, 1, NB), 256, 0, stream>>>(w1, b1, x,  y1,  64, 256, 1);
  gemm1x1<<<dim3(64, 2, NB), 256, 0, stream>>>(w2, b2, y1, y2, 128,  64, 1);
  gemm1x1<<<dim3(64, 4, NB), 256, 0, stream>>>(w3, b3, y2, xf, 256, 128, 1);
  // q, k, v through one fp32 scratch slot, converted immediately
  gemm1x1<<<dim3(64, 4, NB), 256, 0, stream>>>(wq, bq, xf, scr, 256, 256, 0);
  transpose_cvt<<<dim3(64, 4, NB), 256, 0, stream>>>(scr, qTh);
  gemm1x1<<<dim3(64, 4, NB), 256, 0, stream>>>(wk, bk, xf, scr, 256, 256, 0);
  transpose_cvt<<<dim3(64, 4, NB), 256, 0, stream>>>(scr, kTh);
  gemm1x1<<<dim3(64, 4, NB), 256, 0, stream>>>(wv, bv, xf, scr, 256, 256, 0);
  cvt_bf16<<<2048, 256, 0, stream>>>(scr, vTh, (long)(SZ / 8));
  // conv branch (t1 reuses scr; cb lives in d_out)
  conv3x3<<<dim3(64, 4, NB), 256, 0, stream>>>(xf, wb1, bb1, scr, 1);
  conv3x3<<<dim3(64, 4, NB), 256, 0, stream>>>(scr, wb2, bb2, out, 0);
  // attention
  attn_rowstats<<<dim3(64, NB), 256, 0, stream>>>(kTh, qTh, Mrow, Zrow);
  attn_pass2<<<dim3(64, NB), 256, 0, stream>>>(kTh, qTh, vTh, Mrow, Zrow,
                                               alpha, beta, out);
}

// Round 3
// 842.293 us; speedup vs baseline: 7.1535x; 2.4762x over previous
//
#include <hip/hip_runtime.h>
#include <cstdint>

// AttCM R2: 3x3 convs moved to fp16 MFMA implicit GEMM (fp16 chosen over bf16
// for the 8x mantissa: conv-branch error budget demands it). Attention stays
// bf16 MFMA (R1, verified). gemm1x1 stack still fp32 (next target).
// Shapes: B=8, C=256, HW=4096.

#define HW 4096
#define NB 8

typedef __attribute__((ext_vector_type(8))) short short8;      // 8 bf16
typedef __attribute__((ext_vector_type(8))) _Float16 half8;    // 8 fp16
typedef __attribute__((ext_vector_type(4))) float f32x4;       // MFMA C/D

static __device__ __forceinline__ unsigned short f2bf(float x) {
  unsigned u = __float_as_uint(x);
  u += 0x7FFFu + ((u >> 16) & 1u);
  return (unsigned short)(u >> 16);
}
static __device__ __forceinline__ unsigned short f2h(float x) {
  _Float16 h = (_Float16)x;
  return __builtin_bit_cast(unsigned short, h);
}

// ---------------- 1x1 conv as GEMM (fp32, unchanged) ----------------
__global__ __launch_bounds__(256) void gemm1x1(
    const float* __restrict__ W, const float* __restrict__ bias,
    const float* __restrict__ X, float* __restrict__ Y,
    int M, int K, int doRelu) {
  __shared__ float As[16][64];
  __shared__ float Bs[16][64];
  const int b  = blockIdx.z;
  const int m0 = blockIdx.y * 64;
  const int n0 = blockIdx.x * 64;
  const int tid = threadIdx.x;
  const int tx = tid & 15, ty = tid >> 4;
  const int lo = tid & 63, hi = tid >> 6;
  const float* Xb = X + (size_t)b * K * HW;
  float acc[4][4] = {};
  for (int k0 = 0; k0 < K; k0 += 16) {
#pragma unroll
    for (int it = 0; it < 4; it++) {
      const int kk = hi + it * 4;
      As[kk][lo] = W[(size_t)(m0 + lo) * K + k0 + kk];
      Bs[kk][lo] = Xb[(size_t)(k0 + kk) * HW + n0 + lo];
    }
    __syncthreads();
#pragma unroll
    for (int kk = 0; kk < 16; kk++) {
      float a[4], bv[4];
#pragma unroll
      for (int i = 0; i < 4; i++) a[i] = As[kk][ty * 4 + i];
#pragma unroll
      for (int j = 0; j < 4; j++) bv[j] = Bs[kk][tx * 4 + j];
#pragma unroll
      for (int i = 0; i < 4; i++)
#pragma unroll
        for (int j = 0; j < 4; j++)
          acc[i][j] = fmaf(a[i], bv[j], acc[i][j]);
    }
    __syncthreads();
  }
  float* Yb = Y + (size_t)b * M * HW;
#pragma unroll
  for (int i = 0; i < 4; i++) {
    const int m = m0 + ty * 4 + i;
    const float bb = bias[m];
#pragma unroll
    for (int j = 0; j < 4; j++) {
      float v = acc[i][j] + bb;
      if (doRelu) v = fmaxf(v, 0.0f);
      Yb[(size_t)m * HW + n0 + tx * 4 + j] = v;
    }
  }
}

// ---------------- weight reorder: OIHW fp32 -> [o][tap][c] fp16 ----------------
__global__ __launch_bounds__(256) void wreorder(
    const float* __restrict__ w, unsigned short* __restrict__ wA) {
  const int o = blockIdx.x;
  const int c = threadIdx.x;
  const float* wp = w + ((size_t)o * 256 + c) * 9;
#pragma unroll
  for (int tap = 0; tap < 9; tap++)
    wA[((size_t)o * 9 + tap) * 256 + c] = f2h(wp[tap]);
}

// ---------------- fp32 [b][c][p] -> bf16 transposed [b][p][c] ----------------
__global__ __launch_bounds__(256) void transpose_cvt(
    const float* __restrict__ in, unsigned short* __restrict__ outT) {
  __shared__ float Ts[64][65];
  const int t0 = blockIdx.x * 64;
  const int c0 = blockIdx.y * 64;
  const int b  = blockIdx.z;
  const int tid = threadIdx.x;
#pragma unroll
  for (int it = 0; it < 4; it++) {
    int id = tid + it * 256;
    int c = id >> 4, f4 = id & 15;
    float4 v = *(const float4*)(in + ((size_t)(b * 256 + c0 + c)) * HW + t0 + f4 * 4);
    Ts[c][f4 * 4 + 0] = v.x; Ts[c][f4 * 4 + 1] = v.y;
    Ts[c][f4 * 4 + 2] = v.z; Ts[c][f4 * 4 + 3] = v.w;
  }
  __syncthreads();
#pragma unroll
  for (int it = 0; it < 2; it++) {
    int id = tid + it * 256;
    int t = id >> 3, ch = id & 7;
    unsigned short h[8];
#pragma unroll
    for (int e = 0; e < 8; e++) h[e] = f2bf(Ts[ch * 8 + e][t]);
    int4 pk;
    pk.x = (int)((unsigned)h[0] | ((unsigned)h[1] << 16));
    pk.y = (int)((unsigned)h[2] | ((unsigned)h[3] << 16));
    pk.z = (int)((unsigned)h[4] | ((unsigned)h[5] << 16));
    pk.w = (int)((unsigned)h[6] | ((unsigned)h[7] << 16));
    ((int4*)outT)[((size_t)b * HW + t0 + t) * 32 + (c0 >> 3) + ch] = pk;
  }
}

// ---------------- fp32 [b][c][p] -> fp16 transposed [b][p][c] ----------------
__global__ __launch_bounds__(256) void transpose_cvt_h(
    const float* __restrict__ in, unsigned short* __restrict__ outT) {
  __shared__ float Ts[64][65];
  const int t0 = blockIdx.x * 64;
  const int c0 = blockIdx.y * 64;
  const int b  = blockIdx.z;
  const int tid = threadIdx.x;
#pragma unroll
  for (int it = 0; it < 4; it++) {
    int id = tid + it * 256;
    int c = id >> 4, f4 = id & 15;
    float4 v = *(const float4*)(in + ((size_t)(b * 256 + c0 + c)) * HW + t0 + f4 * 4);
    Ts[c][f4 * 4 + 0] = v.x; Ts[c][f4 * 4 + 1] = v.y;
    Ts[c][f4 * 4 + 2] = v.z; Ts[c][f4 * 4 + 3] = v.w;
  }
  __syncthreads();
#pragma unroll
  for (int it = 0; it < 2; it++) {
    int id = tid + it * 256;
    int t = id >> 3, ch = id & 7;
    unsigned short h[8];
#pragma unroll
    for (int e = 0; e < 8; e++) h[e] = f2h(Ts[ch * 8 + e][t]);
    int4 pk;
    pk.x = (int)((unsigned)h[0] | ((unsigned)h[1] << 16));
    pk.y = (int)((unsigned)h[2] | ((unsigned)h[3] << 16));
    pk.z = (int)((unsigned)h[4] | ((unsigned)h[5] << 16));
    pk.w = (int)((unsigned)h[6] | ((unsigned)h[7] << 16));
    ((int4*)outT)[((size_t)b * HW + t0 + t) * 32 + (c0 >> 3) + ch] = pk;
  }
}

// ---------------- fp32 -> bf16 (same layout) ----------------
__global__ void cvt_bf16(const float* __restrict__ in,
                         unsigned short* __restrict__ o, long n8) {
  long i = (long)blockIdx.x * blockDim.x + threadIdx.x;
  const long stride = (long)gridDim.x * blockDim.x;
  const float4* i4 = (const float4*)in;
  for (; i < n8; i += stride) {
    float4 a = i4[2 * i], b = i4[2 * i + 1];
    int4 pk;
    pk.x = (int)((unsigned)f2bf(a.x) | ((unsigned)f2bf(a.y) << 16));
    pk.y = (int)((unsigned)f2bf(a.z) | ((unsigned)f2bf(a.w) << 16));
    pk.z = (int)((unsigned)f2bf(b.x) | ((unsigned)f2bf(b.y) << 16));
    pk.w = (int)((unsigned)f2bf(b.z) | ((unsigned)f2bf(b.w) << 16));
    ((int4*)o)[i] = pk;
  }
}

// ---------------- 3x3 conv, fp16 MFMA implicit GEMM ----------------
// Block: 64 oc x 256 px (4 image rows; wave w <-> row y0+w). K = 8 c-chunks
// of 32 x 9 taps. LDS: weights [tap][64oc][4ch] 36.9KB + input [6][66][4ch]
// 25.3KB, both 2-col/2-oc superblock XOR-swizzled for conflict-free b128.
__global__ __launch_bounds__(256, 2) void conv3x3_mfma(
    const unsigned short* __restrict__ inT,  // fp16 [b][4096][256]
    const unsigned short* __restrict__ wA,   // fp16 [256o][9tap][256c]
    const float* __restrict__ bias,
    unsigned short* __restrict__ outT,       // mode 0: fp16 [b][4096][256], relu
    float* __restrict__ outN,                // mode 1: fp32 [b][256][4096]
    int mode) {
  __shared__ int4 wS[2304];    // [tap][32 sb][8 slots]
  __shared__ int4 inS[1584];   // [6 rows][33 sb][8 slots]
  const int y0 = blockIdx.x * 4;
  const int o0 = blockIdx.y * 64;
  const int b  = blockIdx.z;
  const int tid = threadIdx.x;
  const int w = tid >> 6, l = tid & 63;
  const int l4 = l >> 4, l15 = l & 15;
  const int4* inT4 = (const int4*)inT + (size_t)b * 4096 * 32;
  const int4* wA4  = (const int4*)wA;
  f32x4 acc[4][4];
#pragma unroll
  for (int i = 0; i < 4; i++)
#pragma unroll
    for (int j = 0; j < 4; j++) acc[i][j] = {0.f, 0.f, 0.f, 0.f};

  for (int c0 = 0; c0 < 256; c0 += 32) {
    __syncthreads();
    // stage weights: 64oc x 9tap x 32c = 2304 int4
#pragma unroll
    for (int it = 0; it < 9; it++) {
      int id = it * 256 + tid;
      int ch = id & 3;
      int r  = id >> 2;          // 0..575
      int tap = r % 9, ol = r / 9;
      int sbw = tap * 32 + (ol >> 1);
      int slot = (4 * (ol & 1) + ch) ^ (sbw & 7);
      wS[sbw * 8 + slot] = wA4[((size_t)(o0 + ol) * 9 + tap) * 32 + (c0 >> 3) + ch];
    }
    // stage input rows y0-1 .. y0+4, 32 channels
#pragma unroll
    for (int it = 0; it < 6; it++) {
      int ch = tid & 3;
      int col = tid >> 2;        // 0..63
      int yimg = y0 + it - 1;
      int4 v = {0, 0, 0, 0};
      if (yimg >= 0 && yimg < 64)
        v = inT4[(size_t)(yimg * 64 + col) * 32 + (c0 >> 3) + ch];
      int cl = col + 1;
      int sb = it * 33 + (cl >> 1);
      int slot = (4 * (cl & 1) + ch) ^ (sb & 7);
      inS[sb * 8 + slot] = v;
    }
    if (tid < 48) {              // zero halo cols (x=-1, x=64)
      int row = tid >> 3;
      int cl = ((tid >> 2) & 1) ? 65 : 0;
      int ch = tid & 3;
      int sb = row * 33 + (cl >> 1);
      int slot = (4 * (cl & 1) + ch) ^ (sb & 7);
      inS[sb * 8 + slot] = {0, 0, 0, 0};
    }
    __syncthreads();
#pragma unroll
    for (int tap = 0; tap < 9; tap++) {
      const int dy = tap / 3, dx = tap % 3;
      half8 a[4], bf[4];
#pragma unroll
      for (int mf = 0; mf < 4; mf++) {
        int oc = mf * 16 + l15;
        int sbw = tap * 32 + (oc >> 1);
        a[mf] = ((const half8*)wS)[sbw * 8 + ((4 * (oc & 1) + l4) ^ (sbw & 7))];
      }
#pragma unroll
      for (int nf = 0; nf < 4; nf++) {
        int cl = nf * 16 + l15 + dx;
        int row = w + dy;
        int sb = row * 33 + (cl >> 1);
        bf[nf] = ((const half8*)inS)[sb * 8 + ((4 * (cl & 1) + l4) ^ (sb & 7))];
      }
#pragma unroll
      for (int mf = 0; mf < 4; mf++)
#pragma unroll
        for (int nf = 0; nf < 4; nf++)
          acc[mf][nf] = __builtin_amdgcn_mfma_f32_16x16x32_f16(a[mf], bf[nf], acc[mf][nf], 0, 0, 0);
    }
  }
  // epilogue: D row = l4*4+reg (oc), col = l15 (px)
  const int p_base = (y0 + w) * 64;
#pragma unroll
  for (int mf = 0; mf < 4; mf++) {
    const int ocb = o0 + mf * 16 + l4 * 4;
    const f32x4 bv = *(const f32x4*)(bias + ocb);
#pragma unroll
    for (int nf = 0; nf < 4; nf++) {
      const int p = p_base + nf * 16 + l15;
      if (mode == 0) {
        unsigned short h[4];
#pragma unroll
        for (int r = 0; r < 4; r++)
          h[r] = f2h(fmaxf(acc[mf][nf][r] + bv[r], 0.0f));
        unsigned long long pk = (unsigned long long)h[0] |
                                ((unsigned long long)h[1] << 16) |
                                ((unsigned long long)h[2] << 32) |
                                ((unsigned long long)h[3] << 48);
        *(unsigned long long*)(outT + ((size_t)b * 4096 + p) * 256 + ocb) = pk;
      } else {
#pragma unroll
        for (int r = 0; r < 4; r++)
          outN[((size_t)(b * 256 + ocb + r)) * HW + p] = acc[mf][nf][r] + bv[r];
      }
    }
  }
}

// ---------------- attention pass 1 (MFMA, unchanged from R1) --------
__global__ __launch_bounds__(256) void attn_rowstats(
    const unsigned short* __restrict__ kT, const unsigned short* __restrict__ qT,
    float* __restrict__ Mrow, float* __restrict__ Zrow) {
  __shared__ int4 qs4[64][32];
  const int b = blockIdx.y;
  const int r0 = blockIdx.x * 64;
  const int tid = threadIdx.x;
  const int w = tid >> 6, l = tid & 63;
  const int l4 = l >> 4, l15 = l & 15;
  const int4* qT4 = (const int4*)qT + (size_t)b * HW * 32;
  const short8* kT8 = (const short8*)kT + ((size_t)b * HW + r0) * 32;
  short8 afr[8];
#pragma unroll
  for (int ks = 0; ks < 8; ks++)
    afr[ks] = kT8[(size_t)(w * 16 + l15) * 32 + ks * 4 + l4];
  float m[4], z[4];
#pragma unroll
  for (int i = 0; i < 4; i++) { m[i] = -1e30f; z[i] = 0.0f; }
  for (int t0 = 0; t0 < HW; t0 += 64) {
    __syncthreads();
#pragma unroll
    for (int it = 0; it < 8; it++) {
      int id = tid + it * 256;
      int row = id >> 5, ch = id & 31;
      qs4[row][ch ^ (row & 7)] = qT4[(size_t)(t0 + row) * 32 + ch];
    }
    __syncthreads();
    f32x4 acc[4] = {{0.f,0.f,0.f,0.f},{0.f,0.f,0.f,0.f},
                    {0.f,0.f,0.f,0.f},{0.f,0.f,0.f,0.f}};
#pragma unroll
    for (int ks = 0; ks < 8; ks++) {
#pragma unroll
      for (int nf = 0; nf < 4; nf++) {
        int t = nf * 16 + l15;
        short8 bq = ((const short8*)qs4)[t * 32 + ((ks * 4 + l4) ^ (t & 7))];
        acc[nf] = __builtin_amdgcn_mfma_f32_16x16x32_bf16(afr[ks], bq, acc[nf], 0, 0, 0);
      }
    }
#pragma unroll
    for (int nf = 0; nf < 4; nf++)
#pragma unroll
      for (int r = 0; r < 4; r++) {
        float sv = acc[nf][r];
        if (sv > m[r]) { z[r] *= __expf(m[r] - sv); m[r] = sv; }
        z[r] += __expf(sv - m[r]);
      }
  }
#pragma unroll
  for (int r = 0; r < 4; r++) {
    for (int off = 1; off < 16; off <<= 1) {
      float mo = __shfl_xor(m[r], off, 16);
      float zo = __shfl_xor(z[r], off, 16);
      float mn = fmaxf(m[r], mo);
      z[r] = z[r] * __expf(m[r] - mn) + zo * __expf(mo - mn);
      m[r] = mn;
    }
  }
  if (l15 == 0) {
#pragma unroll
    for (int r = 0; r < 4; r++) {
      int rr = r0 + w * 16 + l4 * 4 + r;
      Mrow[(size_t)b * HW + rr] = m[r];
      Zrow[(size_t)b * HW + rr] = 1.0f / z[r];
    }
  }
}

// ---------------- attention pass 2 (MFMA, unchanged from R1) --------
__global__ __launch_bounds__(256, 2) void attn_pass2(
    const unsigned short* __restrict__ kT, const unsigned short* __restrict__ qT,
    const unsigned short* __restrict__ vB, const float* __restrict__ Mrow,
    const float* __restrict__ Zrow, const float* __restrict__ alphap,
    const float* __restrict__ betap, float* __restrict__ out) {
  __shared__ int4 qs4[64][32];
  __shared__ int4 kvs4[1024];
  __shared__ int4 ps4[64][16];
  const int b = blockIdx.y;
  const int t0 = blockIdx.x * 64;
  const int tid = threadIdx.x;
  const int w = tid >> 6, l = tid & 63;
  const int l4 = l >> 4, l15 = l & 15;
  const int4* qT4 = (const int4*)qT + ((size_t)b * HW + t0) * 32;
  const int4* kT4 = (const int4*)kT + (size_t)b * HW * 32;
  const int4* vB4 = (const int4*)vB;
  const float* Mb = Mrow + (size_t)b * HW;
  const float* Zb = Zrow + (size_t)b * HW;
#pragma unroll
  for (int it = 0; it < 8; it++) {
    int id = tid + it * 256;
    int row = id >> 5, ch = id & 31;
    qs4[row][ch ^ (row & 7)] = qT4[(size_t)row * 32 + ch];
  }
  f32x4 acc_o[4][4];
#pragma unroll
  for (int i = 0; i < 4; i++)
#pragma unroll
    for (int j = 0; j < 4; j++) acc_o[i][j] = {0.f, 0.f, 0.f, 0.f};
  __syncthreads();

  for (int r0 = 0; r0 < HW; r0 += 128) {
    f32x4 acc_s[2][4];
#pragma unroll
    for (int i = 0; i < 2; i++)
#pragma unroll
      for (int j = 0; j < 4; j++) acc_s[i][j] = {0.f, 0.f, 0.f, 0.f};
    for (int cc = 0; cc < 4; cc++) {
      __syncthreads();
#pragma unroll
      for (int it = 0; it < 4; it++) {
        int id = tid + it * 256;
        int row = id >> 3, ch = id & 7;
        kvs4[row * 8 + (ch ^ (row & 7))] = kT4[(size_t)(r0 + row) * 32 + cc * 8 + ch];
      }
      __syncthreads();
#pragma unroll
      for (int kk = 0; kk < 2; kk++) {
        short8 bq[4];
#pragma unroll
        for (int nf = 0; nf < 4; nf++) {
          int t = nf * 16 + l15;
          bq[nf] = ((const short8*)qs4)[t * 32 + (((cc * 2 + kk) * 4 + l4) ^ (t & 7))];
        }
#pragma unroll
        for (int mfl = 0; mfl < 2; mfl++) {
          int r = w * 32 + mfl * 16 + l15;
          short8 ak = ((const short8*)kvs4)[r * 8 + ((kk * 4 + l4) ^ (r & 7))];
#pragma unroll
          for (int nf = 0; nf < 4; nf++)
            acc_s[mfl][nf] = __builtin_amdgcn_mfma_f32_16x16x32_bf16(ak, bq[nf], acc_s[mfl][nf], 0, 0, 0);
        }
      }
    }
#pragma unroll
    for (int mfl = 0; mfl < 2; mfl++) {
      int rbase = r0 + w * 32 + mfl * 16 + l4 * 4;
      f32x4 Mv = *(const f32x4*)(Mb + rbase);
      f32x4 Zv = *(const f32x4*)(Zb + rbase);
      int slot = w * 8 + mfl * 4 + l4;
#pragma unroll
      for (int nf = 0; nf < 4; nf++) {
        int t = nf * 16 + l15;
        unsigned lo = (unsigned)f2bf(__expf(acc_s[mfl][nf][0] - Mv[0]) * Zv[0])
                    | ((unsigned)f2bf(__expf(acc_s[mfl][nf][1] - Mv[1]) * Zv[1]) << 16);
        unsigned hi = (unsigned)f2bf(__expf(acc_s[mfl][nf][2] - Mv[2]) * Zv[2])
                    | ((unsigned)f2bf(__expf(acc_s[mfl][nf][3] - Mv[3]) * Zv[3]) << 16);
        int ch = slot >> 1;
        int fslot = ((ch ^ (t & 7)) << 1) | (slot & 1);
        ((unsigned long long*)ps4)[(size_t)t * 32 + fslot] =
            ((unsigned long long)hi << 32) | (unsigned long long)lo;
      }
    }
#pragma unroll
    for (int cc4 = 0; cc4 < 4; cc4++) {
      __syncthreads();
#pragma unroll
      for (int it = 0; it < 4; it++) {
        int id = tid + it * 256;
        int row = id >> 4, ch = id & 15;
        kvs4[row * 16 + (ch ^ (row & 7))] =
            vB4[((size_t)(b * 256) + cc4 * 64 + row) * 512 + (r0 >> 3) + ch];
      }
      __syncthreads();
#pragma unroll
      for (int ks = 0; ks < 4; ks++) {
        int c = w * 16 + l15;
        short8 av = ((const short8*)kvs4)[c * 16 + ((ks * 4 + l4) ^ (c & 7))];
#pragma unroll
        for (int nf = 0; nf < 4; nf++) {
          int t = nf * 16 + l15;
          short8 bp = ((const short8*)ps4)[t * 16 + ((ks * 4 + l4) ^ (t & 7))];
          acc_o[cc4][nf] = __builtin_amdgcn_mfma_f32_16x16x32_bf16(av, bp, acc_o[cc4][nf], 0, 0, 0);
        }
      }
    }
  }
  const float alpha = alphap[0], beta = betap[0];
#pragma unroll
  for (int cc4 = 0; cc4 < 4; cc4++) {
    int cbase = cc4 * 64 + w * 16 + l4 * 4;
#pragma unroll
    for (int nf = 0; nf < 4; nf++) {
      int t = t0 + nf * 16 + l15;
#pragma unroll
      for (int r = 0; r < 4; r++) {
        size_t idx = ((size_t)(b * 256 + cbase + r)) * HW + t;
        out[idx] = alpha * out[idx] + beta * acc_o[cc4][nf][r];
      }
    }
  }
}

extern "C" void kernel_launch(void* const* d_in, const int* in_sizes, int n_in,
                              void* d_out, int out_size, void* d_ws, size_t ws_size,
                              hipStream_t stream) {
  (void)in_sizes; (void)n_in; (void)out_size; (void)ws_size;
  const float* x   = (const float*)d_in[0];
  const float* w1  = (const float*)d_in[1];
  const float* b1  = (const float*)d_in[2];
  const float* w2  = (const float*)d_in[3];
  const float* b2  = (const float*)d_in[4];
  const float* w3  = (const float*)d_in[5];
  const float* b3  = (const float*)d_in[6];
  const float* wb1 = (const float*)d_in[7];
  const float* bb1 = (const float*)d_in[8];
  const float* wb2 = (const float*)d_in[9];
  const float* bb2 = (const float*)d_in[10];
  const float* wq  = (const float*)d_in[11];
  const float* bq  = (const float*)d_in[12];
  const float* wk  = (const float*)d_in[13];
  const float* bk  = (const float*)d_in[14];
  const float* wv  = (const float*)d_in[15];
  const float* bv  = (const float*)d_in[16];
  const float* alpha = (const float*)d_in[17];
  const float* beta  = (const float*)d_in[18];
  float* out = (float*)d_out;
  float* ws  = (float*)d_ws;

  // ws (floats): xf[SZ] | scr[SZ] | qT,kT,vT bf16 (1.5*SZ) | M,Z | wA1,wA2 fp16
  const size_t SZ = (size_t)NB * 256 * HW;   // 8,388,608
  float* xf  = ws;
  float* scr = ws + SZ;                      // y1/y2 -> q/k/v fp32 -> xfT+t1T fp16
  float* y1  = scr;
  float* y2  = scr + SZ / 4;
  unsigned short* qTh = (unsigned short*)(ws + 2 * SZ);
  unsigned short* kTh = qTh + SZ;
  unsigned short* vTh = kTh + SZ;
  float* Mrow = ws + 2 * SZ + (3 * SZ) / 2;
  float* Zrow = Mrow + (size_t)NB * HW;
  unsigned short* wA1h = (unsigned short*)(Zrow + (size_t)NB * HW);
  unsigned short* wA2h = wA1h + (size_t)256 * 9 * 256;
  unsigned short* xfTh = (unsigned short*)scr;            // SZ fp16
  unsigned short* t1Th = (unsigned short*)(scr + SZ / 2); // SZ fp16

  gemm1x1<<<dim3(64, 1, NB), 256, 0, stream>>>(w1, b1, x,  y1,  64, 256, 1);
  gemm1x1<<<dim3(64, 2, NB), 256, 0, stream>>>(w2, b2, y1, y2, 128,  64, 1);
  gemm1x1<<<dim3(64, 4, NB), 256, 0, stream>>>(w3, b3, y2, xf, 256, 128, 1);
  wreorder<<<256, 256, 0, stream>>>(wb1, wA1h);
  wreorder<<<256, 256, 0, stream>>>(wb2, wA2h);
  // q, k, v through fp32 scratch, converted immediately
  gemm1x1<<<dim3(64, 4, NB), 256, 0, stream>>>(wq, bq, xf, scr, 256, 256, 0);
  transpose_cvt<<<dim3(64, 4, NB), 256, 0, stream>>>(scr, qTh);
  gemm1x1<<<dim3(64, 4, NB), 256, 0, stream>>>(wk, bk, xf, scr, 256, 256, 0);
  transpose_cvt<<<dim3(64, 4, NB), 256, 0, stream>>>(scr, kTh);
  gemm1x1<<<dim3(64, 4, NB), 256, 0, stream>>>(wv, bv, xf, scr, 256, 256, 0);
  cvt_bf16<<<2048, 256, 0, stream>>>(scr, vTh, (long)(SZ / 8));
  // conv branch: xf -> fp16 transposed, then 2 MFMA convs (cb -> d_out)
  transpose_cvt_h<<<dim3(64, 4, NB), 256, 0, stream>>>(xf, xfTh);
  conv3x3_mfma<<<dim3(16, 4, NB), 256, 0, stream>>>(xfTh, wA1h, bb1, t1Th, nullptr, 0);
  conv3x3_mfma<<<dim3(16, 4, NB), 256, 0, stream>>>(t1Th, wA2h, bb2, nullptr, out, 1);
  // attention
  attn_rowstats<<<dim3(64, NB), 256, 0, stream>>>(kTh, qTh, Mrow, Zrow);
  attn_pass2<<<dim3(64, NB), 256, 0, stream>>>(kTh, qTh, vTh, Mrow, Zrow,
                                               alpha, beta, out);
}

// Round 4
// 562.125 us; speedup vs baseline: 10.7188x; 1.4984x over previous
//
#include <hip/hip_runtime.h>
#include <cstdint>

// AttCM R3: everything on fp16 MFMA. Front 1x1 stack = fused fp16 GEMMs with
// transposed-layout epilogues (no separate transpose/cvt passes). Attention
// switched bf16->fp16 (8x mantissa, same rate). All per-batch kernels are
// XCD-pinned: gridDim.x == 8 == batch, so flat_wgid % 8 == batch and each
// XCD's 4MB L2 holds exactly one batch's working set (K+V fp16 = 4MB).
// Shapes: B=8, C=256, HW=4096.

#define HW 4096
#define NB 8

typedef __attribute__((ext_vector_type(8))) _Float16 half8;    // 8 fp16 = 4 VGPR
typedef __attribute__((ext_vector_type(4))) float f32x4;       // MFMA C/D

static __device__ __forceinline__ unsigned short f2h(float x) {
  _Float16 h = (_Float16)x;
  return __builtin_bit_cast(unsigned short, h);
}

// ---------------- 1x1 weights fp32 -> fp16, all six packed ----------------
__global__ __launch_bounds__(256) void wcvt6(
    const float* __restrict__ w1, const float* __restrict__ w2,
    const float* __restrict__ w3, const float* __restrict__ wq,
    const float* __restrict__ wk, const float* __restrict__ wv,
    unsigned short* __restrict__ dst) {
  int i = blockIdx.x * 256 + threadIdx.x;  // 992 blocks x 256 = 253952 exactly
  const float* src; int off;
  if      (i <  16384) { src = w1; off = 0; }
  else if (i <  24576) { src = w2; off = 16384; }
  else if (i <  57344) { src = w3; off = 24576; }
  else if (i < 122880) { src = wq; off = 57344; }
  else if (i < 188416) { src = wk; off = 122880; }
  else                 { src = wv; off = 188416; }
  dst[i] = f2h(src[i - off]);
}

// ---------------- conv weight reorder: OIHW fp32 -> [o][tap][c] fp16 --------
__global__ __launch_bounds__(256) void wreorder(
    const float* __restrict__ w, unsigned short* __restrict__ wA) {
  const int o = blockIdx.x;
  const int c = threadIdx.x;
  const float* wp = w + ((size_t)o * 256 + c) * 9;
#pragma unroll
  for (int tap = 0; tap < 9; tap++)
    wA[((size_t)o * 9 + tap) * 256 + c] = f2h(wp[tap]);
}

// ---------------- fp32 [b][c][p] -> fp16 transposed [b][p][c] ----------------
__global__ __launch_bounds__(256) void transpose_cvt_h(
    const float* __restrict__ in, unsigned short* __restrict__ outT) {
  __shared__ float Ts[64][65];
  const int b  = blockIdx.x;
  const int t0 = blockIdx.y * 64;
  const int c0 = blockIdx.z * 64;
  const int tid = threadIdx.x;
#pragma unroll
  for (int it = 0; it < 4; it++) {
    int id = tid + it * 256;
    int c = id >> 4, f4 = id & 15;
    float4 v = *(const float4*)(in + ((size_t)(b * 256 + c0 + c)) * HW + t0 + f4 * 4);
    Ts[c][f4 * 4 + 0] = v.x; Ts[c][f4 * 4 + 1] = v.y;
    Ts[c][f4 * 4 + 2] = v.z; Ts[c][f4 * 4 + 3] = v.w;
  }
  __syncthreads();
#pragma unroll
  for (int it = 0; it < 2; it++) {
    int id = tid + it * 256;
    int t = id >> 3, ch = id & 7;
    unsigned short h[8];
#pragma unroll
    for (int e = 0; e < 8; e++) h[e] = f2h(Ts[ch * 8 + e][t]);
    int4 pk;
    pk.x = (int)((unsigned)h[0] | ((unsigned)h[1] << 16));
    pk.y = (int)((unsigned)h[2] | ((unsigned)h[3] << 16));
    pk.z = (int)((unsigned)h[4] | ((unsigned)h[5] << 16));
    pk.w = (int)((unsigned)h[6] | ((unsigned)h[7] << 16));
    ((int4*)outT)[((size_t)b * HW + t0 + t) * 32 + (c0 >> 3) + ch] = pk;
  }
}

// ---------------- 1x1 conv: fp16 MFMA GEMM, fused layout epilogue ----------
// Y[m][p] = act(sum_c Wh[m][c] * Xt[b][p][c] + bias[m])
// mode 0: store fp16 transposed [b][p][M] (opt relu). mode 1: fp16 natural
// [b][M][4096] (for V; lanes cover consecutive p -> coalesced 2B stores).
__global__ __launch_bounds__(256) void gemm1x1_h(
    const unsigned short* __restrict__ Wh,   // fp16 [M][K]
    const float* __restrict__ bias,
    const unsigned short* __restrict__ Xt,   // fp16 [b][4096][K]
    unsigned short* __restrict__ outT,
    unsigned short* __restrict__ outN,
    int K, int M, int mode, int doRelu) {
  __shared__ int4 WsL[64 * 32];   // [64 m][K/8 granules], swizzled (<=32KB)
  __shared__ int4 XsL[128 * 8];   // [256 p as (p>>1)][8 granules], swizzled 16KB
  const int b  = blockIdx.x;
  const int p0 = blockIdx.y * 256;
  const int m0 = blockIdx.z * 64;
  const int tid = threadIdx.x;
  const int w = tid >> 6, l = tid & 63;
  const int l4 = l >> 4, l15 = l & 15;
  const int KG  = K >> 3;                       // granules (8 fp16) per row
  const int kgl = (K >= 256) ? 5 : (K >= 128) ? 4 : 3;
  const int4* Wh4 = (const int4*)Wh;
  const int4* Xt4 = (const int4*)Xt + (size_t)(b * 4096 + p0) * KG;
  // stage W once
  for (int id = tid; id < 64 * KG; id += 256) {
    int row = id >> kgl, g = id & (KG - 1);
    WsL[row * KG + (g ^ (row & 7))] = Wh4[(size_t)(m0 + row) * KG + g];
  }
  f32x4 acc[4][4];
#pragma unroll
  for (int i = 0; i < 4; i++)
#pragma unroll
    for (int j = 0; j < 4; j++) acc[i][j] = {0.f, 0.f, 0.f, 0.f};
  const int NCC = K >> 5;
  for (int cc = 0; cc < NCC; cc++) {
    __syncthreads();                 // cc=0: also fences W staging
#pragma unroll
    for (int it = 0; it < 4; it++) {
      int id = tid + it * 256;
      int p = id >> 2, ch = id & 3;
      XsL[(p >> 1) * 8 + ((((p & 1) << 2) + ch) ^ ((p >> 1) & 7))] =
          Xt4[(size_t)p * KG + cc * 4 + ch];
    }
    __syncthreads();
    half8 a[4], bx[4];
#pragma unroll
    for (int mf = 0; mf < 4; mf++) {
      int m = mf * 16 + l15;
      a[mf] = ((const half8*)WsL)[m * KG + ((cc * 4 + l4) ^ (m & 7))];
    }
#pragma unroll
    for (int nf = 0; nf < 4; nf++) {
      int p = w * 64 + nf * 16 + l15;
      bx[nf] = ((const half8*)XsL)[(p >> 1) * 8 + ((((p & 1) << 2) + l4) ^ ((p >> 1) & 7))];
    }
#pragma unroll
    for (int mf = 0; mf < 4; mf++)
#pragma unroll
      for (int nf = 0; nf < 4; nf++)
        acc[mf][nf] = __builtin_amdgcn_mfma_f32_16x16x32_f16(a[mf], bx[nf], acc[mf][nf], 0, 0, 0);
  }
  // epilogue: D row = m (l4*4+reg), col = p (l15)
#pragma unroll
  for (int mf = 0; mf < 4; mf++) {
    const int mrow = m0 + mf * 16 + l4 * 4;
    const f32x4 bv = *(const f32x4*)(bias + mrow);
#pragma unroll
    for (int nf = 0; nf < 4; nf++) {
      const int p = p0 + w * 64 + nf * 16 + l15;
      float vr[4];
#pragma unroll
      for (int r = 0; r < 4; r++) {
        float v = acc[mf][nf][r] + bv[r];
        if (doRelu) v = fmaxf(v, 0.0f);
        vr[r] = v;
      }
      if (mode == 0) {
        unsigned long long pk = (unsigned long long)f2h(vr[0]) |
                                ((unsigned long long)f2h(vr[1]) << 16) |
                                ((unsigned long long)f2h(vr[2]) << 32) |
                                ((unsigned long long)f2h(vr[3]) << 48);
        *(unsigned long long*)(outT + ((size_t)b * 4096 + p) * M + mrow) = pk;
      } else {
#pragma unroll
        for (int r = 0; r < 4; r++)
          outN[((size_t)(b * M + mrow + r)) * 4096 + p] = f2h(vr[r]);
      }
    }
  }
}

// ---------------- 3x3 conv, fp16 MFMA implicit GEMM (R2, regridded) --------
__global__ __launch_bounds__(256, 2) void conv3x3_mfma(
    const unsigned short* __restrict__ inT,  // fp16 [b][4096][256]
    const unsigned short* __restrict__ wA,   // fp16 [256o][9tap][256c]
    const float* __restrict__ bias,
    unsigned short* __restrict__ outT,       // mode 0: fp16 [b][4096][256], relu
    float* __restrict__ outN,                // mode 1: fp32 [b][256][4096]
    int mode) {
  __shared__ int4 wS[2304];    // [tap][32 sb][8 slots]
  __shared__ int4 inS[1584];   // [6 rows][33 sb][8 slots]
  const int b  = blockIdx.x;
  const int y0 = blockIdx.y * 4;
  const int o0 = blockIdx.z * 64;
  const int tid = threadIdx.x;
  const int w = tid >> 6, l = tid & 63;
  const int l4 = l >> 4, l15 = l & 15;
  const int4* inT4 = (const int4*)inT + (size_t)b * 4096 * 32;
  const int4* wA4  = (const int4*)wA;
  f32x4 acc[4][4];
#pragma unroll
  for (int i = 0; i < 4; i++)
#pragma unroll
    for (int j = 0; j < 4; j++) acc[i][j] = {0.f, 0.f, 0.f, 0.f};

  for (int c0 = 0; c0 < 256; c0 += 32) {
    __syncthreads();
#pragma unroll
    for (int it = 0; it < 9; it++) {
      int id = it * 256 + tid;
      int ch = id & 3;
      int r  = id >> 2;
      int tap = r % 9, ol = r / 9;
      int sbw = tap * 32 + (ol >> 1);
      int slot = (4 * (ol & 1) + ch) ^ (sbw & 7);
      wS[sbw * 8 + slot] = wA4[((size_t)(o0 + ol) * 9 + tap) * 32 + (c0 >> 3) + ch];
    }
#pragma unroll
    for (int it = 0; it < 6; it++) {
      int ch = tid & 3;
      int col = tid >> 2;
      int yimg = y0 + it - 1;
      int4 v = {0, 0, 0, 0};
      if (yimg >= 0 && yimg < 64)
        v = inT4[(size_t)(yimg * 64 + col) * 32 + (c0 >> 3) + ch];
      int cl = col + 1;
      int sb = it * 33 + (cl >> 1);
      int slot = (4 * (cl & 1) + ch) ^ (sb & 7);
      inS[sb * 8 + slot] = v;
    }
    if (tid < 48) {
      int row = tid >> 3;
      int cl = ((tid >> 2) & 1) ? 65 : 0;
      int ch = tid & 3;
      int sb = row * 33 + (cl >> 1);
      int slot = (4 * (cl & 1) + ch) ^ (sb & 7);
      inS[sb * 8 + slot] = {0, 0, 0, 0};
    }
    __syncthreads();
#pragma unroll
    for (int tap = 0; tap < 9; tap++) {
      const int dy = tap / 3, dx = tap % 3;
      half8 a[4], bf[4];
#pragma unroll
      for (int mf = 0; mf < 4; mf++) {
        int oc = mf * 16 + l15;
        int sbw = tap * 32 + (oc >> 1);
        a[mf] = ((const half8*)wS)[sbw * 8 + ((4 * (oc & 1) + l4) ^ (sbw & 7))];
      }
#pragma unroll
      for (int nf = 0; nf < 4; nf++) {
        int cl = nf * 16 + l15 + dx;
        int row = w + dy;
        int sb = row * 33 + (cl >> 1);
        bf[nf] = ((const half8*)inS)[sb * 8 + ((4 * (cl & 1) + l4) ^ (sb & 7))];
      }
#pragma unroll
      for (int mf = 0; mf < 4; mf++)
#pragma unroll
        for (int nf = 0; nf < 4; nf++)
          acc[mf][nf] = __builtin_amdgcn_mfma_f32_16x16x32_f16(a[mf], bf[nf], acc[mf][nf], 0, 0, 0);
    }
  }
  const int p_base = (y0 + w) * 64;
#pragma unroll
  for (int mf = 0; mf < 4; mf++) {
    const int ocb = o0 + mf * 16 + l4 * 4;
    const f32x4 bv = *(const f32x4*)(bias + ocb);
#pragma unroll
    for (int nf = 0; nf < 4; nf++) {
      const int p = p_base + nf * 16 + l15;
      if (mode == 0) {
        unsigned short h[4];
#pragma unroll
        for (int r = 0; r < 4; r++)
          h[r] = f2h(fmaxf(acc[mf][nf][r] + bv[r], 0.0f));
        unsigned long long pk = (unsigned long long)h[0] |
                                ((unsigned long long)h[1] << 16) |
                                ((unsigned long long)h[2] << 32) |
                                ((unsigned long long)h[3] << 48);
        *(unsigned long long*)(outT + ((size_t)b * 4096 + p) * 256 + ocb) = pk;
      } else {
#pragma unroll
        for (int r = 0; r < 4; r++)
          outN[((size_t)(b * 256 + ocb + r)) * HW + p] = acc[mf][nf][r] + bv[r];
      }
    }
  }
}

// ---------------- attention pass 1 (fp16 MFMA): per-row max & 1/sum(exp) ----
__global__ __launch_bounds__(256) void attn_rowstats(
    const unsigned short* __restrict__ kT, const unsigned short* __restrict__ qT,
    float* __restrict__ Mrow, float* __restrict__ Zrow) {
  __shared__ int4 qs4[64][32];   // [t][c-granule], swizzled
  const int b  = blockIdx.x;
  const int r0 = blockIdx.y * 64;
  const int tid = threadIdx.x;
  const int w = tid >> 6, l = tid & 63;
  const int l4 = l >> 4, l15 = l & 15;
  const int4* qT4 = (const int4*)qT + (size_t)b * HW * 32;
  const half8* kT8 = (const half8*)kT + ((size_t)b * HW + r0) * 32;
  half8 afr[8];                  // wave w owns rows [w*16, w*16+16)
#pragma unroll
  for (int ks = 0; ks < 8; ks++)
    afr[ks] = kT8[(size_t)(w * 16 + l15) * 32 + ks * 4 + l4];
  float m[4], z[4];
#pragma unroll
  for (int i = 0; i < 4; i++) { m[i] = -1e30f; z[i] = 0.0f; }
  for (int t0 = 0; t0 < HW; t0 += 64) {
    __syncthreads();
#pragma unroll
    for (int it = 0; it < 8; it++) {
      int id = tid + it * 256;
      int row = id >> 5, ch = id & 31;
      qs4[row][ch ^ (row & 7)] = qT4[(size_t)(t0 + row) * 32 + ch];
    }
    __syncthreads();
    f32x4 acc[4] = {{0.f,0.f,0.f,0.f},{0.f,0.f,0.f,0.f},
                    {0.f,0.f,0.f,0.f},{0.f,0.f,0.f,0.f}};
#pragma unroll
    for (int ks = 0; ks < 8; ks++) {
#pragma unroll
      for (int nf = 0; nf < 4; nf++) {
        int t = nf * 16 + l15;
        half8 bq = ((const half8*)qs4)[t * 32 + ((ks * 4 + l4) ^ (t & 7))];
        acc[nf] = __builtin_amdgcn_mfma_f32_16x16x32_f16(afr[ks], bq, acc[nf], 0, 0, 0);
      }
    }
#pragma unroll
    for (int nf = 0; nf < 4; nf++)
#pragma unroll
      for (int r = 0; r < 4; r++) {
        float sv = acc[nf][r];
        if (sv > m[r]) { z[r] *= __expf(m[r] - sv); m[r] = sv; }
        z[r] += __expf(sv - m[r]);
      }
  }
#pragma unroll
  for (int r = 0; r < 4; r++) {
    for (int off = 1; off < 16; off <<= 1) {
      float mo = __shfl_xor(m[r], off, 16);
      float zo = __shfl_xor(z[r], off, 16);
      float mn = fmaxf(m[r], mo);
      z[r] = z[r] * __expf(m[r] - mn) + zo * __expf(mo - mn);
      m[r] = mn;
    }
  }
  if (l15 == 0) {
#pragma unroll
    for (int r = 0; r < 4; r++) {
      int rr = r0 + w * 16 + l4 * 4 + r;
      Mrow[(size_t)b * HW + rr] = m[r];
      Zrow[(size_t)b * HW + rr] = 1.0f / z[r];
    }
  }
}

// ---------------- attention pass 2 (fp16 MFMA) + combine --------------------
__global__ __launch_bounds__(256, 2) void attn_pass2(
    const unsigned short* __restrict__ kT, const unsigned short* __restrict__ qT,
    const unsigned short* __restrict__ vB, const float* __restrict__ Mrow,
    const float* __restrict__ Zrow, const float* __restrict__ alphap,
    const float* __restrict__ betap, float* __restrict__ out) {
  __shared__ int4 qs4[64][32];
  __shared__ int4 kvs4[1024];
  __shared__ int4 ps4[64][16];
  const int b  = blockIdx.x;
  const int t0 = blockIdx.y * 64;
  const int tid = threadIdx.x;
  const int w = tid >> 6, l = tid & 63;
  const int l4 = l >> 4, l15 = l & 15;
  const int4* qT4 = (const int4*)qT + ((size_t)b * HW + t0) * 32;
  const int4* kT4 = (const int4*)kT + (size_t)b * HW * 32;
  const int4* vB4 = (const int4*)vB;
  const float* Mb = Mrow + (size_t)b * HW;
  const float* Zb = Zrow + (size_t)b * HW;
#pragma unroll
  for (int it = 0; it < 8; it++) {
    int id = tid + it * 256;
    int row = id >> 5, ch = id & 31;
    qs4[row][ch ^ (row & 7)] = qT4[(size_t)row * 32 + ch];
  }
  f32x4 acc_o[4][4];
#pragma unroll
  for (int i = 0; i < 4; i++)
#pragma unroll
    for (int j = 0; j < 4; j++) acc_o[i][j] = {0.f, 0.f, 0.f, 0.f};
  __syncthreads();

  for (int r0 = 0; r0 < HW; r0 += 128) {
    f32x4 acc_s[2][4];
#pragma unroll
    for (int i = 0; i < 2; i++)
#pragma unroll
      for (int j = 0; j < 4; j++) acc_s[i][j] = {0.f, 0.f, 0.f, 0.f};
    for (int cc = 0; cc < 4; cc++) {
      __syncthreads();
#pragma unroll
      for (int it = 0; it < 4; it++) {
        int id = tid + it * 256;
        int row = id >> 3, ch = id & 7;
        kvs4[row * 8 + (ch ^ (row & 7))] = kT4[(size_t)(r0 + row) * 32 + cc * 8 + ch];
      }
      __syncthreads();
#pragma unroll
      for (int kk = 0; kk < 2; kk++) {
        half8 bq[4];
#pragma unroll
        for (int nf = 0; nf < 4; nf++) {
          int t = nf * 16 + l15;
          bq[nf] = ((const half8*)qs4)[t * 32 + (((cc * 2 + kk) * 4 + l4) ^ (t & 7))];
        }
#pragma unroll
        for (int mfl = 0; mfl < 2; mfl++) {
          int r = w * 32 + mfl * 16 + l15;
          half8 ak = ((const half8*)kvs4)[r * 8 + ((kk * 4 + l4) ^ (r & 7))];
#pragma unroll
          for (int nf = 0; nf < 4; nf++)
            acc_s[mfl][nf] = __builtin_amdgcn_mfma_f32_16x16x32_f16(ak, bq[nf], acc_s[mfl][nf], 0, 0, 0);
        }
      }
    }
#pragma unroll
    for (int mfl = 0; mfl < 2; mfl++) {
      int rbase = r0 + w * 32 + mfl * 16 + l4 * 4;
      f32x4 Mv = *(const f32x4*)(Mb + rbase);
      f32x4 Zv = *(const f32x4*)(Zb + rbase);
      int slot = w * 8 + mfl * 4 + l4;
#pragma unroll
      for (int nf = 0; nf < 4; nf++) {
        int t = nf * 16 + l15;
        unsigned lo = (unsigned)f2h(__expf(acc_s[mfl][nf][0] - Mv[0]) * Zv[0])
                    | ((unsigned)f2h(__expf(acc_s[mfl][nf][1] - Mv[1]) * Zv[1]) << 16);
        unsigned hi = (unsigned)f2h(__expf(acc_s[mfl][nf][2] - Mv[2]) * Zv[2])
                    | ((unsigned)f2h(__expf(acc_s[mfl][nf][3] - Mv[3]) * Zv[3]) << 16);
        int ch = slot >> 1;
        int fslot = ((ch ^ (t & 7)) << 1) | (slot & 1);
        ((unsigned long long*)ps4)[(size_t)t * 32 + fslot] =
            ((unsigned long long)hi << 32) | (unsigned long long)lo;
      }
    }
#pragma unroll
    for (int cc4 = 0; cc4 < 4; cc4++) {
      __syncthreads();
#pragma unroll
      for (int it = 0; it < 4; it++) {
        int id = tid + it * 256;
        int row = id >> 4, ch = id & 15;
        kvs4[row * 16 + (ch ^ (row & 7))] =
            vB4[((size_t)(b * 256) + cc4 * 64 + row) * 512 + (r0 >> 3) + ch];
      }
      __syncthreads();
#pragma unroll
      for (int ks = 0; ks < 4; ks++) {
        int c = w * 16 + l15;
        half8 av = ((const half8*)kvs4)[c * 16 + ((ks * 4 + l4) ^ (c & 7))];
#pragma unroll
        for (int nf = 0; nf < 4; nf++) {
          int t = nf * 16 + l15;
          half8 bp = ((const half8*)ps4)[t * 16 + ((ks * 4 + l4) ^ (t & 7))];
          acc_o[cc4][nf] = __builtin_amdgcn_mfma_f32_16x16x32_f16(av, bp, acc_o[cc4][nf], 0, 0, 0);
        }
      }
    }
  }
  const float alpha = alphap[0], beta = betap[0];
#pragma unroll
  for (int cc4 = 0; cc4 < 4; cc4++) {
    int cbase = cc4 * 64 + w * 16 + l4 * 4;
#pragma unroll
    for (int nf = 0; nf < 4; nf++) {
      int t = t0 + nf * 16 + l15;
#pragma unroll
      for (int r = 0; r < 4; r++) {
        size_t idx = ((size_t)(b * 256 + cbase + r)) * HW + t;
        out[idx] = alpha * out[idx] + beta * acc_o[cc4][nf][r];
      }
    }
  }
}

extern "C" void kernel_launch(void* const* d_in, const int* in_sizes, int n_in,
                              void* d_out, int out_size, void* d_ws, size_t ws_size,
                              hipStream_t stream) {
  (void)in_sizes; (void)n_in; (void)out_size; (void)ws_size;
  const float* x   = (const float*)d_in[0];
  const float* w1  = (const float*)d_in[1];
  const float* b1  = (const float*)d_in[2];
  const float* w2  = (const float*)d_in[3];
  const float* b2  = (const float*)d_in[4];
  const float* w3  = (const float*)d_in[5];
  const float* b3  = (const float*)d_in[6];
  const float* wb1 = (const float*)d_in[7];
  const float* bb1 = (const float*)d_in[8];
  const float* wb2 = (const float*)d_in[9];
  const float* bb2 = (const float*)d_in[10];
  const float* wq  = (const float*)d_in[11];
  const float* bq  = (const float*)d_in[12];
  const float* wk  = (const float*)d_in[13];
  const float* bk  = (const float*)d_in[14];
  const float* wv  = (const float*)d_in[15];
  const float* bv  = (const float*)d_in[16];
  const float* alpha = (const float*)d_in[17];
  const float* beta  = (const float*)d_in[18];
  float* out = (float*)d_out;

  // ws layout (fp16 halves unless noted). SZH = one [b][4096][256] fp16 tensor.
  const size_t SZH = (size_t)NB * 4096 * 256;   // 8,388,608 halves = 16MB
  unsigned short* wsh = (unsigned short*)d_ws;
  unsigned short* xh  = wsh;                    // x transposed fp16
  unsigned short* xfT = wsh + SZH;
  unsigned short* qT  = wsh + 2 * SZH;
  unsigned short* kT  = wsh + 3 * SZH;
  unsigned short* vN  = wsh + 4 * SZH;          // V natural [b][256][4096]
  unsigned short* y1T = wsh + 5 * SZH;          // [b][4096][64]  (SZH/4)
  unsigned short* y2T = y1T + SZH / 4;          // [b][4096][128] (SZH/2)
  unsigned short* t1T = wsh + 5 * SZH;          // reuses y1/y2 slot later
  float* Mrow = (float*)(wsh + 6 * SZH);
  float* Zrow = Mrow + (size_t)NB * HW;
  unsigned short* wh   = (unsigned short*)(Zrow + (size_t)NB * HW);
  unsigned short* w1h  = wh;                    // [64][256]
  unsigned short* w2h  = wh + 16384;            // [128][64]
  unsigned short* w3h  = wh + 24576;            // [256][128]
  unsigned short* wqh  = wh + 57344;            // [256][256]
  unsigned short* wkh  = wh + 122880;
  unsigned short* wvh  = wh + 188416;
  unsigned short* wA1h = wh + 253952;           // conv [256][9][256]
  unsigned short* wA2h = wA1h + (size_t)256 * 9 * 256;

  wcvt6<<<992, 256, 0, stream>>>(w1, w2, w3, wq, wk, wv, wh);
  wreorder<<<256, 256, 0, stream>>>(wb1, wA1h);
  wreorder<<<256, 256, 0, stream>>>(wb2, wA2h);
  transpose_cvt_h<<<dim3(8, 64, 4), 256, 0, stream>>>(x, xh);
  // front 1x1 stack, all fp16 MFMA, transposed outputs
  gemm1x1_h<<<dim3(8, 16, 1), 256, 0, stream>>>(w1h, b1, xh,  y1T, nullptr, 256,  64, 0, 1);
  gemm1x1_h<<<dim3(8, 16, 2), 256, 0, stream>>>(w2h, b2, y1T, y2T, nullptr,  64, 128, 0, 1);
  gemm1x1_h<<<dim3(8, 16, 4), 256, 0, stream>>>(w3h, b3, y2T, xfT, nullptr, 128, 256, 0, 1);
  gemm1x1_h<<<dim3(8, 16, 4), 256, 0, stream>>>(wqh, bq, xfT, qT,  nullptr, 256, 256, 0, 0);
  gemm1x1_h<<<dim3(8, 16, 4), 256, 0, stream>>>(wkh, bk, xfT, kT,  nullptr, 256, 256, 0, 0);
  gemm1x1_h<<<dim3(8, 16, 4), 256, 0, stream>>>(wvh, bv, xfT, nullptr, vN,  256, 256, 1, 0);
  // conv branch (cb -> d_out fp32 natural)
  conv3x3_mfma<<<dim3(8, 16, 4), 256, 0, stream>>>(xfT, wA1h, bb1, t1T, nullptr, 0);
  conv3x3_mfma<<<dim3(8, 16, 4), 256, 0, stream>>>(t1T, wA2h, bb2, nullptr, out, 1);
  // attention (XCD-pinned: batch == blockIdx.x == XCD)
  attn_rowstats<<<dim3(8, 64), 256, 0, stream>>>(kT, qT, Mrow, Zrow);
  attn_pass2<<<dim3(8, 64), 256, 0, stream>>>(kT, qT, vN, Mrow, Zrow,
                                              alpha, beta, out);
}